// Round 8
// baseline (299.108 us; speedup 1.0000x reference)
//
#include <hip/hip_runtime.h>
#include <math.h>

#define LUTN 1024
#define LUTSCALE 512.0f

// ---------------- K1: prep (zero cnt/d2, M table, LUT, feat->bf16, loc->float4) ----------------

__global__ __launch_bounds__(256) void prep_kernel(
    const float* __restrict__ embed, const float* __restrict__ G_w,
    const float* __restrict__ boundaries, const float* __restrict__ feat,
    const float* __restrict__ loc,
    float* __restrict__ M, int* __restrict__ lut,
    int* __restrict__ d2i, int* __restrict__ cnt,
    unsigned short* __restrict__ featH, float4* __restrict__ loc4, int N) {

    const int gid = blockIdx.x * 256 + threadIdx.x;
    const int gsz = gridDim.x * 256;
    for (int i = gid; i < N; i += gsz) { cnt[i] = 0; d2i[i] = 0; }
    for (int i = gid; i < 4096; i += gsz) {
        int b = i >> 6, f = i & 63;
        float acc = 0.f;
        #pragma unroll
        for (int dd = 0; dd < 32; ++dd) acc += embed[b * 32 + dd] * G_w[f * 32 + dd];
        M[i] = acc;
    }
    for (int i = gid; i < LUTN; i += gsz) {
        float left = (float)i * (1.0f / LUTSCALE);
        int c = 0;
        for (int j = 0; j < 63; ++j) c += (boundaries[j] < left) ? 1 : 0;
        lut[i] = c;
    }
    const int nq = N * 16;   // N*64/4
    for (int i = gid; i < nq; i += gsz) {
        float4 v = ((const float4*)feat)[i];
        unsigned ux = __float_as_uint(v.x), uy = __float_as_uint(v.y);
        unsigned uz = __float_as_uint(v.z), uw = __float_as_uint(v.w);
        ushort4 h;
        h.x = (unsigned short)((ux + 0x7FFFu + ((ux >> 16) & 1u)) >> 16);
        h.y = (unsigned short)((uy + 0x7FFFu + ((uy >> 16) & 1u)) >> 16);
        h.z = (unsigned short)((uz + 0x7FFFu + ((uz >> 16) & 1u)) >> 16);
        h.w = (unsigned short)((uw + 0x7FFFu + ((uw >> 16) & 1u)) >> 16);
        ((ushort4*)featH)[i] = h;
    }
    for (int i = gid; i < N; i += gsz)
        loc4[i] = make_float4(loc[3 * i], loc[3 * i + 1], loc[3 * i + 2], 0.f);
}

// ---------------- K2: edge pass — bucket + rank atomic + d2 atomic, 16-B record ----------------
// recE[e] = {s|i0<<16, i1|i2<<16, i3|rank<<16, pack}   (all ids < 2^16)

__global__ __launch_bounds__(256) void edge_kernel(
    const float4* __restrict__ loc4, const float* __restrict__ boundaries,
    const int* __restrict__ lut,
    const int* __restrict__ src, const int* __restrict__ dst,
    const int* __restrict__ inter,
    int* __restrict__ cnt, int* __restrict__ d2i,
    int4* __restrict__ recE, int E) {

    __shared__ int lut_s[LUTN];
    __shared__ float bl[64];
    ((int4*)lut_s)[threadIdx.x] = ((const int4*)lut)[threadIdx.x];
    if (threadIdx.x < 64)
        bl[threadIdx.x] = (threadIdx.x < 63) ? boundaries[threadIdx.x] : 3.4e38f;
    __syncthreads();

    const int e = blockIdx.x * 256 + threadIdx.x;
    if (e >= E) return;

    const int s = src[e], d = dst[e];
    const int4 ii = ((const int4*)inter)[e];

    const float4 ps = loc4[s];
    float dist[5];
    {
        float4 pd = loc4[d];
        float dx = pd.x - ps.x, dy = pd.y - ps.y, dz = pd.z - ps.z;
        dist[0] = sqrtf(dx * dx + dy * dy + dz * dz);
    }
    const int id4[4] = {ii.x, ii.y, ii.z, ii.w};
    #pragma unroll
    for (int j = 0; j < 4; ++j) {
        float4 pt = loc4[id4[j]];
        float dx = pt.x - ps.x, dy = pt.y - ps.y, dz = pt.z - ps.z;
        dist[1 + j] = sqrtf(dx * dx + dy * dy + dz * dz);
    }
    unsigned pack = 0;
    #pragma unroll
    for (int q = 0; q < 5; ++q) {
        float dq = dist[q];
        int cell = (int)(dq * LUTSCALE);
        cell = (cell > LUTN - 1) ? (LUTN - 1) : cell;
        int b = lut_s[cell];
        while (b < 63 && bl[b] < dq) ++b;
        while (b > 0 && bl[b - 1] >= dq) --b;
        pack |= ((unsigned)b) << (6 * q);
    }

    const int r = atomicAdd(&cnt[d], 1);   // rank within dst segment (deg << 65536)
    atomicAdd(&d2i[s], 1);                 // out-degree histogram

    recE[e] = make_int4(s | (ii.x << 16), ii.y | (ii.z << 16), ii.w | (r << 16), (int)pack);
}

// ---------------- K3: single-block exclusive scan of cnt -> startv ----------------

__global__ __launch_bounds__(1024) void scan_kernel(
    const int* __restrict__ cnt, int* __restrict__ startv, int N) {

    __shared__ int wsum[16];
    const int t = threadIdx.x, lane = t & 63, wv = t >> 6;
    const int C = (N + 1023) / 1024;           // 49
    const int b0 = t * C, b1 = min(b0 + C, N);

    int s = 0;
    for (int i = b0; i < b1; ++i) s += cnt[i];

    int x = s;
    #pragma unroll
    for (int off = 1; off < 64; off <<= 1) { int y = __shfl_up(x, off); if (lane >= off) x += y; }
    if (lane == 63) wsum[wv] = x;
    __syncthreads();
    if (t < 16) {
        int w = wsum[t], xx = w;
        #pragma unroll
        for (int off = 1; off < 16; off <<= 1) { int y = __shfl_up(xx, off); if (t >= off) xx += y; }
        wsum[t] = xx - w;
    }
    __syncthreads();
    int run = x + wsum[wv] - s;                // exclusive prefix for this thread's chunk
    for (int i = b0; i < b1; ++i) {
        startv[i] = run;
        run += cnt[i];
    }
}

// ---------------- K4: atomic-free scatter (16 B), rank -> w(bf16) swap ----------------

__global__ __launch_bounds__(256) void scatter_kernel(
    const int4* __restrict__ recE, const int* __restrict__ dst,
    const int* __restrict__ startv, const int* __restrict__ d2i,
    int4* __restrict__ rec, int E) {

    const int e = blockIdx.x * 256 + threadIdx.x;
    if (e >= E) return;
    const int4 a = recE[e];
    const int s = a.x & 0xFFFF;
    const int r = ((unsigned)a.z) >> 16;
    const int pos = startv[dst[e]] + r;
    const float w = rsqrtf(fmaxf((float)d2i[s], 1.0f));
    unsigned uw = __float_as_uint(w);
    unsigned wb = (uw + 0x7FFFu + ((uw >> 16) & 1u)) & 0xFFFF0000u;   // bf16 in high half
    rec[pos] = make_int4(a.x, a.y, (a.z & 0xFFFF) | (int)wb, a.w);
}

// ---------------- K5: wave-per-node gather (bf16 feat) + accumulate ----------------

__global__ __launch_bounds__(256) void node_kernel(
    const unsigned short* __restrict__ featH, const float* __restrict__ M,
    const int* __restrict__ cnt, const int* __restrict__ startv,
    const int4* __restrict__ rec, float* __restrict__ cat,
    float* __restrict__ swb, int N) {

    __shared__ float Ms[4096];
    #pragma unroll
    for (int i = 0; i < 4; ++i)
        ((float4*)Ms)[threadIdx.x + 256 * i] = ((const float4*)M)[threadIdx.x + 256 * i];
    __syncthreads();

    const int lane = threadIdx.x & 63;
    const int wid  = threadIdx.x >> 6;
    const int d    = blockIdx.x * 4 + wid;
    if (d >= N) return;

    const int deg  = __builtin_amdgcn_readfirstlane(cnt[d]);
    const int base = __builtin_amdgcn_readfirstlane(startv[d]);
    const int4* rp = rec + base;

    float acc0 = 0.f, acc1 = 0.f, sw = 0.f;

    #pragma unroll 4
    for (int k = 0; k < deg; ++k) {
        const int4 r = rp[k];                       // uniform -> s_load_dwordx4
        const int s  = r.x & 0xFFFF;
        const int i0 = ((unsigned)r.x) >> 16;
        const int i1 = r.y & 0xFFFF;
        const int i2 = ((unsigned)r.y) >> 16;
        const int i3 = r.z & 0xFFFF;
        const float w = __uint_as_float((unsigned)r.z & 0xFFFF0000u);
        const unsigned pk = (unsigned)r.w;

        const float fs = __uint_as_float(((unsigned)featH[(size_t)s  * 64 + lane]) << 16);
        const float f0 = __uint_as_float(((unsigned)featH[(size_t)i0 * 64 + lane]) << 16);
        const float f1 = __uint_as_float(((unsigned)featH[(size_t)i1 * 64 + lane]) << 16);
        const float f2 = __uint_as_float(((unsigned)featH[(size_t)i2 * 64 + lane]) << 16);
        const float f3 = __uint_as_float(((unsigned)featH[(size_t)i3 * 64 + lane]) << 16);
        const float m0 = Ms[(pk & 63u) * 64 + lane];
        const float m1 = Ms[((pk >> 6) & 63u) * 64 + lane];
        const float m2 = Ms[((pk >> 12) & 63u) * 64 + lane];
        const float m3 = Ms[((pk >> 18) & 63u) * 64 + lane];
        const float m4 = Ms[((pk >> 24) & 63u) * 64 + lane];

        acc0 = fmaf(m0 * fs, w, acc0);
        float t = m1 * f0 + m2 * f1 + m3 * f2 + m4 * f3;
        acc1 = fmaf(0.25f * t, w, acc1);
        sw += w;
    }

    cat[(size_t)d * 128 + lane]      = acc0;
    cat[(size_t)d * 128 + 64 + lane] = acc1;
    if (lane == 0) swb[d] = sw;
}

// ---------------- K6: epilogue GEMM  out = d0 * (cat @ agg_w^T + bias*sw) ----------------

__global__ __launch_bounds__(256) void epilogue_kernel(
    const float* __restrict__ cat, const float* __restrict__ agg_w,
    const float* __restrict__ agg_b, const float* __restrict__ swb,
    const int* __restrict__ cnt, float* __restrict__ out, int N) {

    const int lane = threadIdx.x & 63;
    const int wid  = threadIdx.x >> 6;

    float4 aw[32];
    const float4* awp = (const float4*)(agg_w + (size_t)lane * 128);
    #pragma unroll
    for (int i = 0; i < 32; ++i) aw[i] = awp[i];
    const float bias = agg_b[lane];

    const int gw = blockIdx.x * 4 + wid;
    const int stride = gridDim.x * 4;

    for (int d0i = gw; d0i < N; d0i += stride) {
        const int du = __builtin_amdgcn_readfirstlane(d0i);
        const float* cp = cat + (size_t)du * 128;
        float a0 = bias * swb[du], a1 = 0.f, a2 = 0.f, a3 = 0.f;
        #pragma unroll
        for (int k4 = 0; k4 < 32; k4 += 4) {
            float4 c0 = ((const float4*)cp)[k4];
            float4 c1 = ((const float4*)cp)[k4 + 1];
            float4 c2 = ((const float4*)cp)[k4 + 2];
            float4 c3 = ((const float4*)cp)[k4 + 3];
            a0 = fmaf(aw[k4].x, c0.x, a0); a0 = fmaf(aw[k4].y, c0.y, a0);
            a0 = fmaf(aw[k4].z, c0.z, a0); a0 = fmaf(aw[k4].w, c0.w, a0);
            a1 = fmaf(aw[k4+1].x, c1.x, a1); a1 = fmaf(aw[k4+1].y, c1.y, a1);
            a1 = fmaf(aw[k4+1].z, c1.z, a1); a1 = fmaf(aw[k4+1].w, c1.w, a1);
            a2 = fmaf(aw[k4+2].x, c2.x, a2); a2 = fmaf(aw[k4+2].y, c2.y, a2);
            a2 = fmaf(aw[k4+2].z, c2.z, a2); a2 = fmaf(aw[k4+2].w, c2.w, a2);
            a3 = fmaf(aw[k4+3].x, c3.x, a3); a3 = fmaf(aw[k4+3].y, c3.y, a3);
            a3 = fmaf(aw[k4+3].z, c3.z, a3); a3 = fmaf(aw[k4+3].w, c3.w, a3);
        }
        const float d0v = rsqrtf(fmaxf((float)cnt[du], 1.0f));
        out[(size_t)du * 64 + lane] = d0v * ((a0 + a1) + (a2 + a3));
    }
}

// ---------------- launch ----------------

extern "C" void kernel_launch(void* const* d_in, const int* in_sizes, int n_in,
                              void* d_out, int out_size, void* d_ws, size_t ws_size,
                              hipStream_t stream) {
    const float* feat       = (const float*)d_in[0];
    const float* loc        = (const float*)d_in[1];
    const float* boundaries = (const float*)d_in[2];
    const float* embed      = (const float*)d_in[3];
    const float* G_w        = (const float*)d_in[4];
    const float* agg_w      = (const float*)d_in[5];
    const float* agg_b      = (const float*)d_in[6];
    const int*   src        = (const int*)d_in[7];
    const int*   dst        = (const int*)d_in[8];
    const int*   inter      = (const int*)d_in[9];

    const int N = in_sizes[0] / 64;   // 50000 (< 2^16, required by 16-bit id packing)
    const int E = in_sizes[7];        // 500000

    char* w = (char*)d_ws;
    auto take = [&](size_t bytes) { char* p = w; w += (bytes + 15) & ~(size_t)15; return p; };
    float*          M      = (float*)take(4096 * 4);
    int*            lut    = (int*)  take(LUTN * 4);
    int*            d2i    = (int*)  take((size_t)N * 4);
    int*            cnt    = (int*)  take((size_t)N * 4);
    int*            startv = (int*)  take((size_t)N * 4);
    int4*           recE   = (int4*) take((size_t)E * 16);
    int4*           rec    = (int4*) take((size_t)E * 16);
    float*          cat    = (float*)take((size_t)N * 128 * 4);
    float*          swb    = (float*)take((size_t)N * 4);
    unsigned short* featH  = (unsigned short*)take((size_t)N * 64 * 2);
    float4*         loc4   = (float4*)take((size_t)N * 16);
    float*          out    = (float*)d_out;

    const int eb = (E + 255) / 256;     // 1954

    prep_kernel<<<1024, 256, 0, stream>>>(embed, G_w, boundaries, feat, loc,
                                          M, lut, d2i, cnt, featH, loc4, N);
    edge_kernel<<<eb, 256, 0, stream>>>(loc4, boundaries, lut, src, dst, inter,
                                        cnt, d2i, recE, E);
    scan_kernel<<<1, 1024, 0, stream>>>(cnt, startv, N);
    scatter_kernel<<<eb, 256, 0, stream>>>(recE, dst, startv, d2i, rec, E);
    node_kernel<<<(N + 3) / 4, 256, 0, stream>>>(featH, M, cnt, startv, rec, cat, swb, N);
    epilogue_kernel<<<768, 256, 0, stream>>>(cat, agg_w, agg_b, swb, cnt, out, N);
}

// Round 9
// 233.428 us; speedup vs baseline: 1.2814x; 1.2814x over previous
//
#include <hip/hip_runtime.h>
#include <math.h>

#define LUTN 1024
#define LUTSCALE 512.0f

// ---------------- K1: prep (zero cnt/d2, M table, LUT, feat->bf16, loc->float4) ----------------

__global__ __launch_bounds__(256) void prep_kernel(
    const float* __restrict__ embed, const float* __restrict__ G_w,
    const float* __restrict__ boundaries, const float* __restrict__ feat,
    const float* __restrict__ loc,
    float* __restrict__ M, int* __restrict__ lut,
    int* __restrict__ d2i, int* __restrict__ cnt,
    unsigned short* __restrict__ featH, float4* __restrict__ loc4, int N) {

    const int gid = blockIdx.x * 256 + threadIdx.x;
    const int gsz = gridDim.x * 256;
    for (int i = gid; i < N; i += gsz) { cnt[i] = 0; d2i[i] = 0; }
    for (int i = gid; i < 4096; i += gsz) {
        int b = i >> 6, f = i & 63;
        float acc = 0.f;
        #pragma unroll
        for (int dd = 0; dd < 32; ++dd) acc += embed[b * 32 + dd] * G_w[f * 32 + dd];
        M[i] = acc;
    }
    for (int i = gid; i < LUTN; i += gsz) {
        float left = (float)i * (1.0f / LUTSCALE);
        int c = 0;
        for (int j = 0; j < 63; ++j) c += (boundaries[j] < left) ? 1 : 0;
        lut[i] = c;
    }
    const int nq = N * 16;   // N*64/4
    for (int i = gid; i < nq; i += gsz) {
        float4 v = ((const float4*)feat)[i];
        unsigned ux = __float_as_uint(v.x), uy = __float_as_uint(v.y);
        unsigned uz = __float_as_uint(v.z), uw = __float_as_uint(v.w);
        ushort4 h;
        h.x = (unsigned short)((ux + 0x7FFFu + ((ux >> 16) & 1u)) >> 16);
        h.y = (unsigned short)((uy + 0x7FFFu + ((uy >> 16) & 1u)) >> 16);
        h.z = (unsigned short)((uz + 0x7FFFu + ((uz >> 16) & 1u)) >> 16);
        h.w = (unsigned short)((uw + 0x7FFFu + ((uw >> 16) & 1u)) >> 16);
        ((ushort4*)featH)[i] = h;
    }
    for (int i = gid; i < N; i += gsz)
        loc4[i] = make_float4(loc[3 * i], loc[3 * i + 1], loc[3 * i + 2], 0.f);
}

// ---------------- K2: edge pass — bucket + rank atomic + d2 atomic, 16-B record ----------------
// recE[e] = {s|i0<<16, i1|i2<<16, i3|rank<<16, pack}   (all ids < 2^16)

__global__ __launch_bounds__(256) void edge_kernel(
    const float4* __restrict__ loc4, const float* __restrict__ boundaries,
    const int* __restrict__ lut,
    const int* __restrict__ src, const int* __restrict__ dst,
    const int* __restrict__ inter,
    int* __restrict__ cnt, int* __restrict__ d2i,
    int4* __restrict__ recE, int E) {

    __shared__ int lut_s[LUTN];
    __shared__ float bl[64];
    ((int4*)lut_s)[threadIdx.x] = ((const int4*)lut)[threadIdx.x];
    if (threadIdx.x < 64)
        bl[threadIdx.x] = (threadIdx.x < 63) ? boundaries[threadIdx.x] : 3.4e38f;
    __syncthreads();

    const int e = blockIdx.x * 256 + threadIdx.x;
    if (e >= E) return;

    const int s = src[e], d = dst[e];
    const int4 ii = ((const int4*)inter)[e];

    const float4 ps = loc4[s];
    float dist[5];
    {
        float4 pd = loc4[d];
        float dx = pd.x - ps.x, dy = pd.y - ps.y, dz = pd.z - ps.z;
        dist[0] = sqrtf(dx * dx + dy * dy + dz * dz);
    }
    const int id4[4] = {ii.x, ii.y, ii.z, ii.w};
    #pragma unroll
    for (int j = 0; j < 4; ++j) {
        float4 pt = loc4[id4[j]];
        float dx = pt.x - ps.x, dy = pt.y - ps.y, dz = pt.z - ps.z;
        dist[1 + j] = sqrtf(dx * dx + dy * dy + dz * dz);
    }
    unsigned pack = 0;
    #pragma unroll
    for (int q = 0; q < 5; ++q) {
        float dq = dist[q];
        int cell = (int)(dq * LUTSCALE);
        cell = (cell > LUTN - 1) ? (LUTN - 1) : cell;
        int b = lut_s[cell];
        while (b < 63 && bl[b] < dq) ++b;
        while (b > 0 && bl[b - 1] >= dq) --b;
        pack |= ((unsigned)b) << (6 * q);
    }

    const int r = atomicAdd(&cnt[d], 1);   // rank within dst segment (deg << 65536)
    atomicAdd(&d2i[s], 1);                 // out-degree histogram

    recE[e] = make_int4(s | (ii.x << 16), ii.y | (ii.z << 16), ii.w | (r << 16), (int)pack);
}

// ---------------- K3: parallel chunk scan: startv block-local excl + part totals ----------------

__global__ __launch_bounds__(1024) void scan_block_kernel(
    const int* __restrict__ cnt, int* __restrict__ startv,
    int* __restrict__ part, int N) {

    __shared__ int wsum[16];
    const int t = threadIdx.x, lane = t & 63, wv = t >> 6;
    const int i = blockIdx.x * 1024 + t;

    int v = (i < N) ? cnt[i] : 0;
    int x = v;
    #pragma unroll
    for (int off = 1; off < 64; off <<= 1) { int y = __shfl_up(x, off); if (lane >= off) x += y; }
    if (lane == 63) wsum[wv] = x;
    __syncthreads();
    if (t < 16) {
        int w = wsum[t], xx = w;
        #pragma unroll
        for (int off = 1; off < 16; off <<= 1) { int y = __shfl_up(xx, off); if (t >= off) xx += y; }
        wsum[t] = xx - w;
    }
    __syncthreads();
    int incl = x + wsum[wv];
    if (i < N) startv[i] = incl - v;             // chunk-local exclusive
    if (t == 1023) part[blockIdx.x] = incl;      // chunk total
}

// shared helper: chunk-offset prefix (nb <= 64) into smem
__device__ __forceinline__ void load_chunkoff(const int* __restrict__ part, int nb,
                                              int* __restrict__ co) {
    if (threadIdx.x < 64) {
        int v = (threadIdx.x < nb) ? part[threadIdx.x] : 0;
        int x = v;
        #pragma unroll
        for (int off = 1; off < 64; off <<= 1) {
            int y = __shfl_up(x, off);
            if ((threadIdx.x & 63) >= off) x += y;
        }
        co[threadIdx.x] = x - v;                 // exclusive
    }
    __syncthreads();
}

// ---------------- K4: atomic-free scatter (16 B), rank -> w(bf16) swap ----------------

__global__ __launch_bounds__(256) void scatter_kernel(
    const int4* __restrict__ recE, const int* __restrict__ dst,
    const int* __restrict__ startv, const int* __restrict__ part,
    const int* __restrict__ d2i, int4* __restrict__ rec, int E, int nb) {

    __shared__ int co[64];
    load_chunkoff(part, nb, co);

    const int e = blockIdx.x * 256 + threadIdx.x;
    if (e >= E) return;
    const int4 a = recE[e];
    const int s = a.x & 0xFFFF;
    const int r = ((unsigned)a.z) >> 16;
    const int d = dst[e];
    const int pos = startv[d] + co[d >> 10] + r;
    const float w = rsqrtf(fmaxf((float)d2i[s], 1.0f));
    unsigned uw = __float_as_uint(w);
    unsigned wb = (uw + 0x7FFFu + ((uw >> 16) & 1u)) & 0xFFFF0000u;   // bf16 in high half
    rec[pos] = make_int4(a.x, a.y, (a.z & 0xFFFF) | (int)wb, a.w);
}

// ---------------- K5: wave-per-node gather (bf16 feat) + accumulate ----------------

__global__ __launch_bounds__(256) void node_kernel(
    const unsigned short* __restrict__ featH, const float* __restrict__ M,
    const int* __restrict__ cnt, const int* __restrict__ startv,
    const int* __restrict__ part, const int4* __restrict__ rec,
    float* __restrict__ cat, float* __restrict__ swb, int N, int nb) {

    __shared__ float Ms[4096];
    __shared__ int co[64];
    #pragma unroll
    for (int i = 0; i < 4; ++i)
        ((float4*)Ms)[threadIdx.x + 256 * i] = ((const float4*)M)[threadIdx.x + 256 * i];
    load_chunkoff(part, nb, co);   // includes the __syncthreads for Ms too

    const int lane = threadIdx.x & 63;
    const int wid  = threadIdx.x >> 6;
    const int d    = blockIdx.x * 4 + wid;
    if (d >= N) return;

    const int deg  = __builtin_amdgcn_readfirstlane(cnt[d]);
    const int base = __builtin_amdgcn_readfirstlane(startv[d] + co[d >> 10]);
    const int4* rp = rec + base;

    float acc0 = 0.f, acc1 = 0.f, sw = 0.f;

    #pragma unroll 4
    for (int k = 0; k < deg; ++k) {
        const int4 r = rp[k];                       // wave-uniform
        const int s  = r.x & 0xFFFF;
        const int i0 = ((unsigned)r.x) >> 16;
        const int i1 = r.y & 0xFFFF;
        const int i2 = ((unsigned)r.y) >> 16;
        const int i3 = r.z & 0xFFFF;
        const float w = __uint_as_float((unsigned)r.z & 0xFFFF0000u);
        const unsigned pk = (unsigned)r.w;

        const float fs = __uint_as_float(((unsigned)featH[(size_t)s  * 64 + lane]) << 16);
        const float f0 = __uint_as_float(((unsigned)featH[(size_t)i0 * 64 + lane]) << 16);
        const float f1 = __uint_as_float(((unsigned)featH[(size_t)i1 * 64 + lane]) << 16);
        const float f2 = __uint_as_float(((unsigned)featH[(size_t)i2 * 64 + lane]) << 16);
        const float f3 = __uint_as_float(((unsigned)featH[(size_t)i3 * 64 + lane]) << 16);
        const float m0 = Ms[(pk & 63u) * 64 + lane];
        const float m1 = Ms[((pk >> 6) & 63u) * 64 + lane];
        const float m2 = Ms[((pk >> 12) & 63u) * 64 + lane];
        const float m3 = Ms[((pk >> 18) & 63u) * 64 + lane];
        const float m4 = Ms[((pk >> 24) & 63u) * 64 + lane];

        acc0 = fmaf(m0 * fs, w, acc0);
        float t = m1 * f0 + m2 * f1 + m3 * f2 + m4 * f3;
        acc1 = fmaf(0.25f * t, w, acc1);
        sw += w;
    }

    cat[(size_t)d * 128 + lane]      = acc0;
    cat[(size_t)d * 128 + 64 + lane] = acc1;
    if (lane == 0) swb[d] = sw;
}

// ---------------- K6: epilogue GEMM  out = d0 * (cat @ agg_w^T + bias*sw) ----------------

__global__ __launch_bounds__(256) void epilogue_kernel(
    const float* __restrict__ cat, const float* __restrict__ agg_w,
    const float* __restrict__ agg_b, const float* __restrict__ swb,
    const int* __restrict__ cnt, float* __restrict__ out, int N) {

    const int lane = threadIdx.x & 63;
    const int wid  = threadIdx.x >> 6;

    float4 aw[32];
    const float4* awp = (const float4*)(agg_w + (size_t)lane * 128);
    #pragma unroll
    for (int i = 0; i < 32; ++i) aw[i] = awp[i];
    const float bias = agg_b[lane];

    const int gw = blockIdx.x * 4 + wid;
    const int stride = gridDim.x * 4;

    for (int d0i = gw; d0i < N; d0i += stride) {
        const int du = __builtin_amdgcn_readfirstlane(d0i);
        const float* cp = cat + (size_t)du * 128;
        float a0 = bias * swb[du], a1 = 0.f, a2 = 0.f, a3 = 0.f;
        #pragma unroll
        for (int k4 = 0; k4 < 32; k4 += 4) {
            float4 c0 = ((const float4*)cp)[k4];
            float4 c1 = ((const float4*)cp)[k4 + 1];
            float4 c2 = ((const float4*)cp)[k4 + 2];
            float4 c3 = ((const float4*)cp)[k4 + 3];
            a0 = fmaf(aw[k4].x, c0.x, a0); a0 = fmaf(aw[k4].y, c0.y, a0);
            a0 = fmaf(aw[k4].z, c0.z, a0); a0 = fmaf(aw[k4].w, c0.w, a0);
            a1 = fmaf(aw[k4+1].x, c1.x, a1); a1 = fmaf(aw[k4+1].y, c1.y, a1);
            a1 = fmaf(aw[k4+1].z, c1.z, a1); a1 = fmaf(aw[k4+1].w, c1.w, a1);
            a2 = fmaf(aw[k4+2].x, c2.x, a2); a2 = fmaf(aw[k4+2].y, c2.y, a2);
            a2 = fmaf(aw[k4+2].z, c2.z, a2); a2 = fmaf(aw[k4+2].w, c2.w, a2);
            a3 = fmaf(aw[k4+3].x, c3.x, a3); a3 = fmaf(aw[k4+3].y, c3.y, a3);
            a3 = fmaf(aw[k4+3].z, c3.z, a3); a3 = fmaf(aw[k4+3].w, c3.w, a3);
        }
        const float d0v = rsqrtf(fmaxf((float)cnt[du], 1.0f));
        out[(size_t)du * 64 + lane] = d0v * ((a0 + a1) + (a2 + a3));
    }
}

// ---------------- launch ----------------

extern "C" void kernel_launch(void* const* d_in, const int* in_sizes, int n_in,
                              void* d_out, int out_size, void* d_ws, size_t ws_size,
                              hipStream_t stream) {
    const float* feat       = (const float*)d_in[0];
    const float* loc        = (const float*)d_in[1];
    const float* boundaries = (const float*)d_in[2];
    const float* embed      = (const float*)d_in[3];
    const float* G_w        = (const float*)d_in[4];
    const float* agg_w      = (const float*)d_in[5];
    const float* agg_b      = (const float*)d_in[6];
    const int*   src        = (const int*)d_in[7];
    const int*   dst        = (const int*)d_in[8];
    const int*   inter      = (const int*)d_in[9];

    const int N = in_sizes[0] / 64;   // 50000 (< 2^16, required by 16-bit id packing)
    const int E = in_sizes[7];        // 500000

    char* w = (char*)d_ws;
    auto take = [&](size_t bytes) { char* p = w; w += (bytes + 15) & ~(size_t)15; return p; };
    float*          M      = (float*)take(4096 * 4);
    int*            lut    = (int*)  take(LUTN * 4);
    int*            d2i    = (int*)  take((size_t)N * 4);
    int*            cnt    = (int*)  take((size_t)N * 4);
    int*            startv = (int*)  take((size_t)N * 4);
    int*            part   = (int*)  take(64 * 4);
    int4*           recE   = (int4*) take((size_t)E * 16);
    int4*           rec    = (int4*) take((size_t)E * 16);
    float*          cat    = (float*)take((size_t)N * 128 * 4);
    float*          swb    = (float*)take((size_t)N * 4);
    unsigned short* featH  = (unsigned short*)take((size_t)N * 64 * 2);
    float4*         loc4   = (float4*)take((size_t)N * 16);
    float*          out    = (float*)d_out;

    const int eb = (E + 255) / 256;     // 1954
    const int nb = (N + 1023) / 1024;   // 49 (<= 64 required by chunkoff helper)

    prep_kernel<<<1024, 256, 0, stream>>>(embed, G_w, boundaries, feat, loc,
                                          M, lut, d2i, cnt, featH, loc4, N);
    edge_kernel<<<eb, 256, 0, stream>>>(loc4, boundaries, lut, src, dst, inter,
                                        cnt, d2i, recE, E);
    scan_block_kernel<<<nb, 1024, 0, stream>>>(cnt, startv, part, N);
    scatter_kernel<<<eb, 256, 0, stream>>>(recE, dst, startv, part, d2i, rec, E, nb);
    node_kernel<<<(N + 3) / 4, 256, 0, stream>>>(featH, M, cnt, startv, part, rec,
                                                 cat, swb, N, nb);
    epilogue_kernel<<<768, 256, 0, stream>>>(cat, agg_w, agg_b, swb, cnt, out, N);
}